// Round 1
// baseline (23163.306 us; speedup 1.0000x reference)
//
#include <hip/hip_runtime.h>
#include <hip/hip_bf16.h>

// Problem constants (fixed by the reference)
#define L     4096
#define E     512
#define HID   1024
#define HH    512          // H per direction
#define G4    2048         // 4*H gate rows
#define T_TAG 7
#define START_TAG 4
#define STOP_TAG  5
#define NEGV  (-10000.0f)

#define NBLK 16            // blocks per direction in the recurrence

// ---------------------------------------------------------------------------
// Kernel 1: xg[t][j] = emb[sentence[t]] . w_ih[j] + b_ih[j] + b_hh[j]
// for both directions.  Tiled fp32 GEMM, tile 64x64, K-chunks of 32.
// grid (L/64, G4/64, 2), block 256.
// ---------------------------------------------------------------------------
__global__ __launch_bounds__(256)
void xg_kernel(const int* __restrict__ sentence, const float* __restrict__ emb,
               const float* __restrict__ wih_f, const float* __restrict__ bih_f,
               const float* __restrict__ bhh_f,
               const float* __restrict__ wih_b, const float* __restrict__ bih_b,
               const float* __restrict__ bhh_b,
               float* __restrict__ xg_f, float* __restrict__ xg_b)
{
    const int dir = blockIdx.z;
    const float* __restrict__ wih = dir ? wih_b : wih_f;
    const float* __restrict__ bih = dir ? bih_b : bih_f;
    const float* __restrict__ bhh = dir ? bhh_b : bhh_f;
    float* __restrict__ xg = dir ? xg_b : xg_f;

    const int t0 = blockIdx.x * 64;
    const int j0 = blockIdx.y * 64;

    __shared__ float As[32][65];   // As[k][i] = x[t0+i][k0+k]
    __shared__ float Bs[32][65];   // Bs[k][j] = wih[j0+j][k0+k]
    __shared__ int   sent[64];

    const int tid = threadIdx.x;
    if (tid < 64) sent[tid] = sentence[t0 + tid];
    __syncthreads();

    const int tx = tid & 15;       // output col group
    const int ty = tid >> 4;       // output row group

    float acc[4][4];
#pragma unroll
    for (int a = 0; a < 4; a++)
#pragma unroll
        for (int b = 0; b < 4; b++) acc[a][b] = 0.f;

    for (int k0 = 0; k0 < E; k0 += 32) {
        __syncthreads();
#pragma unroll
        for (int q = 0; q < 2; q++) {
            const int f  = q * 256 + tid;     // 0..511
            const int i  = f >> 3;            // 0..63
            const int k4 = (f & 7) * 4;       // 0..28
            const float4 av = *(const float4*)(emb + (size_t)sent[i] * E + k0 + k4);
            As[k4 + 0][i] = av.x; As[k4 + 1][i] = av.y;
            As[k4 + 2][i] = av.z; As[k4 + 3][i] = av.w;
            const float4 bv = *(const float4*)(wih + (size_t)(j0 + i) * E + k0 + k4);
            Bs[k4 + 0][i] = bv.x; Bs[k4 + 1][i] = bv.y;
            Bs[k4 + 2][i] = bv.z; Bs[k4 + 3][i] = bv.w;
        }
        __syncthreads();
#pragma unroll
        for (int k = 0; k < 32; k++) {
            float a[4], b[4];
#pragma unroll
            for (int ii = 0; ii < 4; ii++) a[ii] = As[k][ty * 4 + ii];
#pragma unroll
            for (int jj = 0; jj < 4; jj++) b[jj] = Bs[k][tx * 4 + jj];
#pragma unroll
            for (int ii = 0; ii < 4; ii++)
#pragma unroll
                for (int jj = 0; jj < 4; jj++) acc[ii][jj] += a[ii] * b[jj];
        }
    }

#pragma unroll
    for (int ii = 0; ii < 4; ii++) {
        const int t = t0 + ty * 4 + ii;
#pragma unroll
        for (int jj = 0; jj < 4; jj++) {
            const int j = j0 + tx * 4 + jj;
            xg[(size_t)t * G4 + j] = acc[ii][jj] + bih[j] + bhh[j];
        }
    }
}

// ---------------------------------------------------------------------------
// Kernel 2: bidirectional LSTM recurrence.  Cooperative, 32 blocks x 512.
// Blocks 0..15 = forward, 16..31 = backward.  Each block owns 32 hidden
// units (their 128 gate rows); W_hh slice lives in registers (128 VGPR/lane).
// Per-step sync: cumulative release/acquire counter per direction; h rows
// are exchanged through hf/hb (agent-scope atomics), which are also the
// kernel outputs.
// ---------------------------------------------------------------------------
__global__ __launch_bounds__(512)
void lstm_kernel(const float* __restrict__ xg_f, const float* __restrict__ xg_b,
                 const float* __restrict__ whh_f, const float* __restrict__ whh_b,
                 float* __restrict__ hf, float* __restrict__ hb, int* cnt)
{
    const int dir = blockIdx.x >> 4;
    const int b   = blockIdx.x & 15;
    const float* __restrict__ xg  = dir ? xg_b  : xg_f;
    const float* __restrict__ whh = dir ? whh_b : whh_f;
    float* __restrict__ hout = dir ? hb : hf;
    int* my_cnt = cnt + dir * 64;

    const int tid  = threadIdx.x;
    const int wave = tid >> 6;       // 0..7
    const int lane = tid & 63;
    const int g    = wave & 3;       // gate type: 0=i 1=f 2=g 3=o
    const int half = wave >> 2;      // unit half
    const int u0   = b * 32 + half * 16;
    const int col0 = lane * 8;

    // weights: w[r][k] = whh[(g*HH + u0 + r)*HH + col0 + k]
    float w[16][8];
#pragma unroll
    for (int r = 0; r < 16; r++) {
        const float4* p = (const float4*)(whh + (size_t)(g * HH + u0 + r) * HH + col0);
        const float4 w0 = p[0], w1 = p[1];
        w[r][0] = w0.x; w[r][1] = w0.y; w[r][2] = w0.z; w[r][3] = w0.w;
        w[r][4] = w1.x; w[r][5] = w1.y; w[r][6] = w1.z; w[r][7] = w1.w;
    }

    __shared__ float glds[8][16];
    float c_state = 0.f;             // live only for tid < 32

    for (int s = 0; s < L; s++) {
        const int t = dir ? (L - 1 - s) : s;

        if (s > 0) {
            if (tid == 0) {
                while (__hip_atomic_load(my_cnt, __ATOMIC_ACQUIRE,
                                         __HIP_MEMORY_SCOPE_AGENT) < NBLK * s) {
                    __builtin_amdgcn_s_sleep(1);
                }
            }
            __syncthreads();
        }

        float h[8];
        if (s == 0) {
#pragma unroll
            for (int k = 0; k < 8; k++) h[k] = 0.f;
        } else {
            const int tp = dir ? (t + 1) : (t - 1);
            const float* hp = hout + (size_t)tp * HH + col0;
#pragma unroll
            for (int k = 0; k < 8; k++)
                h[k] = __hip_atomic_load(hp + k, __ATOMIC_RELAXED,
                                         __HIP_MEMORY_SCOPE_AGENT);
        }

        float acc[16];
#pragma unroll
        for (int r = 0; r < 16; r++) {
            float a = 0.f;
#pragma unroll
            for (int k = 0; k < 8; k++) a += w[r][k] * h[k];
            acc[r] = a;
        }
#pragma unroll
        for (int m = 1; m < 64; m <<= 1) {
#pragma unroll
            for (int r = 0; r < 16; r++) acc[r] += __shfl_xor(acc[r], m, 64);
        }
        if (lane == 0) {
#pragma unroll
            for (int r = 0; r < 16; r++) glds[wave][r] = acc[r];
        }
        __syncthreads();

        if (tid < 32) {
            const int u  = tid;
            const int uu = b * 32 + u;
            const int wb = (u >> 4) * 4;
            const int r  = u & 15;
            const float* xgt = xg + (size_t)t * G4;
            float iv = glds[wb + 0][r] + xgt[uu];
            float fv = glds[wb + 1][r] + xgt[HH + uu];
            float gv = glds[wb + 2][r] + xgt[2 * HH + uu];
            float ov = glds[wb + 3][r] + xgt[3 * HH + uu];
            iv = 1.f / (1.f + expf(-iv));
            fv = 1.f / (1.f + expf(-fv));
            gv = tanhf(gv);
            ov = 1.f / (1.f + expf(-ov));
            c_state = fv * c_state + iv * gv;
            const float hv = ov * tanhf(c_state);
            __hip_atomic_store(&hout[(size_t)t * HH + uu], hv, __ATOMIC_RELAXED,
                               __HIP_MEMORY_SCOPE_AGENT);
        }
        __syncthreads();
        if (tid == 0)
            __hip_atomic_fetch_add(my_cnt, 1, __ATOMIC_RELEASE,
                                   __HIP_MEMORY_SCOPE_AGENT);
    }
}

// ---------------------------------------------------------------------------
// Kernel 3: feats[t][i] = [hf[t],hb[t]] . w_out[i] + b_out[i]
// grid L blocks, block 256.  feats stored with stride 8.
// ---------------------------------------------------------------------------
__global__ __launch_bounds__(256)
void feats_kernel(const float* __restrict__ hf, const float* __restrict__ hb,
                  const float* __restrict__ wout, const float* __restrict__ bout,
                  float* __restrict__ feats)
{
    const int t   = blockIdx.x;
    const int tid = threadIdx.x;

    float acc[T_TAG];
#pragma unroll
    for (int i = 0; i < T_TAG; i++) acc[i] = 0.f;

    for (int c = tid; c < HID; c += 256) {
        const float v = (c < HH) ? hf[(size_t)t * HH + c]
                                 : hb[(size_t)t * HH + (c - HH)];
#pragma unroll
        for (int i = 0; i < T_TAG; i++) acc[i] += v * wout[i * HID + c];
    }
#pragma unroll
    for (int m = 1; m < 64; m <<= 1) {
#pragma unroll
        for (int i = 0; i < T_TAG; i++) acc[i] += __shfl_xor(acc[i], m, 64);
    }

    __shared__ float red[4][T_TAG];
    const int wave = tid >> 6, lane = tid & 63;
    if (lane == 0) {
#pragma unroll
        for (int i = 0; i < T_TAG; i++) red[wave][i] = acc[i];
    }
    __syncthreads();
    if (tid < T_TAG) {
        feats[(size_t)t * 8 + tid] =
            red[0][tid] + red[1][tid] + red[2][tid] + red[3][tid] + bout[tid];
    }
}

// ---------------------------------------------------------------------------
// Kernel 4: Viterbi forward + backtrace.  One wave.
// lanes: i = tid>>3 (dest tag), j = tid&7 (src tag).  First-index argmax
// tie-break to match jnp.argmax.  bp kept in LDS; single-lane backtrace.
// out[0..L-1] = path (floats), out[L] = score.
// ---------------------------------------------------------------------------
__global__ __launch_bounds__(64)
void viterbi_kernel(const float* __restrict__ feats, const float* __restrict__ trans,
                    float* __restrict__ out)
{
    __shared__ unsigned char bp[L][T_TAG];

    const int tid = threadIdx.x;     // 0..63
    const int i = tid >> 3, j = tid & 7;
    const bool valid = (i < T_TAG) && (j < T_TAG);
    const float trij = valid ? trans[i * T_TAG + j] : -1e30f;

    float fv;
    if (j < T_TAG) fv = (j == START_TAG) ? 0.f : NEGV;
    else           fv = -1e30f;

    const int ieff = (i < T_TAG) ? i : 0;
    float fq[8];
#pragma unroll
    for (int p = 0; p < 8; p++) fq[p] = feats[(size_t)p * 8 + ieff];

    for (int t = 0; t < L; t++) {
        const float sc = fv + trij;
        float best = sc; int bj = j;
#pragma unroll
        for (int m = 1; m < 8; m <<= 1) {
            const float ov = __shfl_xor(best, m, 8);
            const int   oj = __shfl_xor(bj, m, 8);
            if (ov > best || (ov == best && oj < bj)) { best = ov; bj = oj; }
        }
        const float f_t = fq[t & 7];
        if (t + 8 < L) fq[t & 7] = feats[(size_t)(t + 8) * 8 + ieff];
        const float fvnew = best + f_t;          // for dest tag == i
        if (valid && j == 0) bp[t][i] = (unsigned char)bj;
        const float nf = __shfl(fvnew, (j < T_TAG) ? j * 8 : 0, 64);
        fv = (j < T_TAG) ? nf : -1e30f;
    }

    // terminal: lane j (group 0) holds fv[j]
    float term = fv + ((j < T_TAG) ? trans[STOP_TAG * T_TAG + j] : -1e30f);
    float bestt = term; int bt = j;
#pragma unroll
    for (int m = 1; m < 8; m <<= 1) {
        const float ov = __shfl_xor(bestt, m, 8);
        const int   oj = __shfl_xor(bt, m, 8);
        if (ov > bestt || (ov == bestt && oj < bt)) { bestt = ov; bt = oj; }
    }

    if (tid == 0) {
        out[L] = bestt;
        int tag = bt;
        out[L - 1] = (float)tag;
        for (int t = L - 1; t >= 1; t--) {
            tag = bp[t][tag];
            out[t - 1] = (float)tag;
        }
    }
}

// ---------------------------------------------------------------------------
extern "C" void kernel_launch(void* const* d_in, const int* in_sizes, int n_in,
                              void* d_out, int out_size, void* d_ws, size_t ws_size,
                              hipStream_t stream)
{
    const int*   sentence = (const int*)  d_in[0];
    const float* emb      = (const float*)d_in[1];
    const float* wih_f    = (const float*)d_in[2];
    const float* whh_f    = (const float*)d_in[3];
    const float* bih_f    = (const float*)d_in[4];
    const float* bhh_f    = (const float*)d_in[5];
    const float* wih_b    = (const float*)d_in[6];
    const float* whh_b    = (const float*)d_in[7];
    const float* bih_b    = (const float*)d_in[8];
    const float* bhh_b    = (const float*)d_in[9];
    const float* wout     = (const float*)d_in[10];
    const float* bout     = (const float*)d_in[11];
    const float* trans    = (const float*)d_in[12];
    float* out = (float*)d_out;

    char* ws = (char*)d_ws;
    int*   cnt    = (int*)ws;                                   // 1 KiB
    float* xg_f   = (float*)(ws + 1024);
    float* xg_b   = xg_f  + (size_t)L * G4;
    float* hfbuf  = xg_b  + (size_t)L * G4;
    float* hbbuf  = hfbuf + (size_t)L * HH;
    float* featsb = hbbuf + (size_t)L * HH;
    // total: 1024 + 2*L*G4*4 + 2*L*HH*4 + L*8*4  ~= 84 MB

    hipMemsetAsync(cnt, 0, 1024, stream);

    hipLaunchKernelGGL(xg_kernel, dim3(L / 64, G4 / 64, 2), dim3(256), 0, stream,
                       sentence, emb, wih_f, bih_f, bhh_f, wih_b, bih_b, bhh_b,
                       xg_f, xg_b);

    void* args[] = { (void*)&xg_f, (void*)&xg_b, (void*)&whh_f, (void*)&whh_b,
                     (void*)&hfbuf, (void*)&hbbuf, (void*)&cnt };
    hipLaunchCooperativeKernel((void*)lstm_kernel, dim3(2 * NBLK), dim3(512),
                               args, 0, stream);

    hipLaunchKernelGGL(feats_kernel, dim3(L), dim3(256), 0, stream,
                       hfbuf, hbbuf, wout, bout, featsb);

    hipLaunchKernelGGL(viterbi_kernel, dim3(1), dim3(64), 0, stream,
                       featsb, trans, out);
}

// Round 2
// 16784.666 us; speedup vs baseline: 1.3800x; 1.3800x over previous
//
#include <hip/hip_runtime.h>
#include <hip/hip_bf16.h>

// Problem constants (fixed by the reference)
#define L     4096
#define E     512
#define HID   1024
#define HH    512          // H per direction
#define G4    2048         // 4*H gate rows
#define T_TAG 7
#define START_TAG 4
#define STOP_TAG  5
#define NEGV  (-10000.0f)

#define NBLK 32            // blocks per direction in the recurrence
#define SENT 0xFFFFFFFFu   // h sentinel: -NaN, unreachable for real h values

// ---------------------------------------------------------------------------
// Kernel 1: xg[t][j] = emb[sentence[t]] . w_ih[j] + b_ih[j] + b_hh[j]
// for both directions.  Tiled fp32 GEMM, tile 64x64, K-chunks of 32.
// grid (L/64, G4/64, 2), block 256.
// ---------------------------------------------------------------------------
__global__ __launch_bounds__(256)
void xg_kernel(const int* __restrict__ sentence, const float* __restrict__ emb,
               const float* __restrict__ wih_f, const float* __restrict__ bih_f,
               const float* __restrict__ bhh_f,
               const float* __restrict__ wih_b, const float* __restrict__ bih_b,
               const float* __restrict__ bhh_b,
               float* __restrict__ xg_f, float* __restrict__ xg_b)
{
    const int dir = blockIdx.z;
    const float* __restrict__ wih = dir ? wih_b : wih_f;
    const float* __restrict__ bih = dir ? bih_b : bih_f;
    const float* __restrict__ bhh = dir ? bhh_b : bhh_f;
    float* __restrict__ xg = dir ? xg_b : xg_f;

    const int t0 = blockIdx.x * 64;
    const int j0 = blockIdx.y * 64;

    __shared__ float As[32][68];   // As[k][i] = x[t0+i][k0+k]   (pad 68: float4-aligned reads)
    __shared__ float Bs[32][68];   // Bs[k][j] = wih[j0+j][k0+k]
    __shared__ int   sent[64];

    const int tid = threadIdx.x;
    if (tid < 64) sent[tid] = sentence[t0 + tid];
    __syncthreads();

    const int tx = tid & 15;       // output col group
    const int ty = tid >> 4;       // output row group

    float acc[4][4];
#pragma unroll
    for (int a = 0; a < 4; a++)
#pragma unroll
        for (int b = 0; b < 4; b++) acc[a][b] = 0.f;

    for (int k0 = 0; k0 < E; k0 += 32) {
        __syncthreads();
#pragma unroll
        for (int q = 0; q < 2; q++) {
            const int f  = q * 256 + tid;     // 0..511
            const int i  = f >> 3;            // 0..63
            const int k4 = (f & 7) * 4;       // 0..28
            const float4 av = *(const float4*)(emb + (size_t)sent[i] * E + k0 + k4);
            As[k4 + 0][i] = av.x; As[k4 + 1][i] = av.y;
            As[k4 + 2][i] = av.z; As[k4 + 3][i] = av.w;
            const float4 bv = *(const float4*)(wih + (size_t)(j0 + i) * E + k0 + k4);
            Bs[k4 + 0][i] = bv.x; Bs[k4 + 1][i] = bv.y;
            Bs[k4 + 2][i] = bv.z; Bs[k4 + 3][i] = bv.w;
        }
        __syncthreads();
#pragma unroll
        for (int k = 0; k < 32; k++) {
            const float4 a4 = *(const float4*)&As[k][ty * 4];
            const float4 b4 = *(const float4*)&Bs[k][tx * 4];
            const float a[4] = { a4.x, a4.y, a4.z, a4.w };
            const float b[4] = { b4.x, b4.y, b4.z, b4.w };
#pragma unroll
            for (int ii = 0; ii < 4; ii++)
#pragma unroll
                for (int jj = 0; jj < 4; jj++) acc[ii][jj] += a[ii] * b[jj];
        }
    }

#pragma unroll
    for (int ii = 0; ii < 4; ii++) {
        const int t = t0 + ty * 4 + ii;
#pragma unroll
        for (int jj = 0; jj < 4; jj++) {
            const int j = j0 + tx * 4 + jj;
            xg[(size_t)t * G4 + j] = acc[ii][jj] + bih[j] + bhh[j];
        }
    }
}

// ---------------------------------------------------------------------------
// Kernel 2: bidirectional LSTM recurrence.  Cooperative, 64 blocks x 512.
// Blocks 0..31 = forward, 32..63 = backward.  Each block owns 16 hidden
// units (64 gate rows); the W_hh slice lives in registers (64 VGPR/lane).
// Sync: pure data-flow.  h buffers are pre-set to a NaN sentinel; producers
// store h words with relaxed agent-scope atomics; each consumer lane polls
// only its own 8 words (8 parallel loads per poll round).  No counters,
// no serialization point.
// ---------------------------------------------------------------------------
__global__ __launch_bounds__(512)
void lstm_kernel(const float* __restrict__ xg_f, const float* __restrict__ xg_b,
                 const float* __restrict__ whh_f, const float* __restrict__ whh_b,
                 float* __restrict__ hf, float* __restrict__ hb)
{
    const int dir = blockIdx.x >> 5;   // 0 fwd, 1 bwd
    const int b   = blockIdx.x & 31;
    const float* __restrict__ xg  = dir ? xg_b  : xg_f;
    const float* __restrict__ whh = dir ? whh_b : whh_f;
    float* __restrict__ hout = dir ? hb : hf;

    const int tid  = threadIdx.x;
    const int wave = tid >> 6;       // 0..7
    const int lane = tid & 63;
    const int g    = wave & 3;       // gate type: 0=i 1=f 2=g 3=o
    const int half = wave >> 2;      // unit half (0: units 0..7, 1: 8..15)
    const int u0   = b * 16 + half * 8;
    const int col0 = lane * 8;

    // weights: w[r][k] = whh[(g*HH + u0 + r)*HH + col0 + k], r=0..7, k=0..7
    float w[8][8];
#pragma unroll
    for (int r = 0; r < 8; r++) {
        const float4* p = (const float4*)(whh + (size_t)(g * HH + u0 + r) * HH + col0);
        const float4 w0 = p[0], w1 = p[1];
        w[r][0] = w0.x; w[r][1] = w0.y; w[r][2] = w0.z; w[r][3] = w0.w;
        w[r][4] = w1.x; w[r][5] = w1.y; w[r][6] = w1.z; w[r][7] = w1.w;
    }

    __shared__ float glds[8][8];
    float c_state = 0.f;             // live only for tid < 16
    const int uu = b * 16 + (tid & 15);

    // xg prefetch registers (tail threads only)
    float xq0 = 0.f, xq1 = 0.f, xq2 = 0.f, xq3 = 0.f;
    if (tid < 16) {
        const float* xgt = xg + (size_t)(dir ? (L - 1) : 0) * G4;
        xq0 = xgt[uu];            xq1 = xgt[HH + uu];
        xq2 = xgt[2 * HH + uu];   xq3 = xgt[3 * HH + uu];
    }

    for (int s = 0; s < L; s++) {
        const int t = dir ? (L - 1 - s) : s;

        float h[8];
        if (s == 0) {
#pragma unroll
            for (int k = 0; k < 8; k++) h[k] = 0.f;
        } else {
            const int tp = dir ? (t + 1) : (t - 1);
            const unsigned int* hp =
                (const unsigned int*)(hout + (size_t)tp * HH + col0);
            unsigned int v[8];
            bool ok;
            do {
                ok = true;
#pragma unroll
                for (int k = 0; k < 8; k++)
                    v[k] = __hip_atomic_load(hp + k, __ATOMIC_RELAXED,
                                             __HIP_MEMORY_SCOPE_AGENT);
#pragma unroll
                for (int k = 0; k < 8; k++) ok &= (v[k] != SENT);
            } while (!ok);
#pragma unroll
            for (int k = 0; k < 8; k++) h[k] = __uint_as_float(v[k]);
        }

        float acc[8];
#pragma unroll
        for (int r = 0; r < 8; r++) {
            float a = 0.f;
#pragma unroll
            for (int k = 0; k < 8; k++) a += w[r][k] * h[k];
            acc[r] = a;
        }
#pragma unroll
        for (int m = 1; m < 64; m <<= 1) {
#pragma unroll
            for (int r = 0; r < 8; r++) acc[r] += __shfl_xor(acc[r], m, 64);
        }
        if (lane == 0) {
#pragma unroll
            for (int r = 0; r < 8; r++) glds[wave][r] = acc[r];
        }
        __syncthreads();

        if (tid < 16) {
            const int hf_ = tid >> 3;      // unit half
            const int r   = tid & 7;
            float iv = glds[hf_ * 4 + 0][r] + xq0;
            float fv = glds[hf_ * 4 + 1][r] + xq1;
            float gv = glds[hf_ * 4 + 2][r] + xq2;
            float ov = glds[hf_ * 4 + 3][r] + xq3;
            iv = 1.f / (1.f + expf(-iv));
            fv = 1.f / (1.f + expf(-fv));
            gv = tanhf(gv);
            ov = 1.f / (1.f + expf(-ov));
            c_state = fv * c_state + iv * gv;
            const float hv = ov * tanhf(c_state);
            __hip_atomic_store((unsigned int*)&hout[(size_t)t * HH + uu],
                               __float_as_uint(hv), __ATOMIC_RELAXED,
                               __HIP_MEMORY_SCOPE_AGENT);
            // prefetch next step's xg (hides under next poll + matvec)
            if (s + 1 < L) {
                const int tn = dir ? (t - 1) : (t + 1);
                const float* xgt = xg + (size_t)tn * G4;
                xq0 = xgt[uu];            xq1 = xgt[HH + uu];
                xq2 = xgt[2 * HH + uu];   xq3 = xgt[3 * HH + uu];
            }
        }
        __syncthreads();
    }
}

// ---------------------------------------------------------------------------
// Kernel 3: feats[t][i] = [hf[t],hb[t]] . w_out[i] + b_out[i]
// grid L blocks, block 256.  feats stored with stride 8.
// ---------------------------------------------------------------------------
__global__ __launch_bounds__(256)
void feats_kernel(const float* __restrict__ hf, const float* __restrict__ hb,
                  const float* __restrict__ wout, const float* __restrict__ bout,
                  float* __restrict__ feats)
{
    const int t   = blockIdx.x;
    const int tid = threadIdx.x;

    float acc[T_TAG];
#pragma unroll
    for (int i = 0; i < T_TAG; i++) acc[i] = 0.f;

    for (int c = tid; c < HID; c += 256) {
        const float v = (c < HH) ? hf[(size_t)t * HH + c]
                                 : hb[(size_t)t * HH + (c - HH)];
#pragma unroll
        for (int i = 0; i < T_TAG; i++) acc[i] += v * wout[i * HID + c];
    }
#pragma unroll
    for (int m = 1; m < 64; m <<= 1) {
#pragma unroll
        for (int i = 0; i < T_TAG; i++) acc[i] += __shfl_xor(acc[i], m, 64);
    }

    __shared__ float red[4][T_TAG];
    const int wave = tid >> 6, lane = tid & 63;
    if (lane == 0) {
#pragma unroll
        for (int i = 0; i < T_TAG; i++) red[wave][i] = acc[i];
    }
    __syncthreads();
    if (tid < T_TAG) {
        feats[(size_t)t * 8 + tid] =
            red[0][tid] + red[1][tid] + red[2][tid] + red[3][tid] + bout[tid];
    }
}

// ---------------------------------------------------------------------------
// Kernel 4: Viterbi forward + backtrace.  One wave.
// lanes: i = tid>>3 (dest tag), j = tid&7 (src tag).  First-index argmax
// tie-break to match jnp.argmax.  bp kept in LDS; single-lane backtrace.
// out[0..L-1] = path (floats), out[L] = score.
// ---------------------------------------------------------------------------
__global__ __launch_bounds__(64)
void viterbi_kernel(const float* __restrict__ feats, const float* __restrict__ trans,
                    float* __restrict__ out)
{
    __shared__ unsigned char bp[L][T_TAG];

    const int tid = threadIdx.x;     // 0..63
    const int i = tid >> 3, j = tid & 7;
    const bool valid = (i < T_TAG) && (j < T_TAG);
    const float trij = valid ? trans[i * T_TAG + j] : -1e30f;

    float fv;
    if (j < T_TAG) fv = (j == START_TAG) ? 0.f : NEGV;
    else           fv = -1e30f;

    const int ieff = (i < T_TAG) ? i : 0;
    float fq[8];
#pragma unroll
    for (int p = 0; p < 8; p++) fq[p] = feats[(size_t)p * 8 + ieff];

    for (int t = 0; t < L; t++) {
        const float sc = fv + trij;
        float best = sc; int bj = j;
#pragma unroll
        for (int m = 1; m < 8; m <<= 1) {
            const float ov = __shfl_xor(best, m, 8);
            const int   oj = __shfl_xor(bj, m, 8);
            if (ov > best || (ov == best && oj < bj)) { best = ov; bj = oj; }
        }
        const float f_t = fq[t & 7];
        if (t + 8 < L) fq[t & 7] = feats[(size_t)(t + 8) * 8 + ieff];
        const float fvnew = best + f_t;          // for dest tag == i
        if (valid && j == 0) bp[t][i] = (unsigned char)bj;
        const float nf = __shfl(fvnew, (j < T_TAG) ? j * 8 : 0, 64);
        fv = (j < T_TAG) ? nf : -1e30f;
    }

    // terminal: lane j (group 0) holds fv[j]
    float term = fv + ((j < T_TAG) ? trans[STOP_TAG * T_TAG + j] : -1e30f);
    float bestt = term; int bt = j;
#pragma unroll
    for (int m = 1; m < 8; m <<= 1) {
        const float ov = __shfl_xor(bestt, m, 8);
        const int   oj = __shfl_xor(bt, m, 8);
        if (ov > bestt || (ov == bestt && oj < bt)) { bestt = ov; bt = oj; }
    }

    if (tid == 0) {
        out[L] = bestt;
        int tag = bt;
        out[L - 1] = (float)tag;
        for (int t = L - 1; t >= 1; t--) {
            tag = bp[t][tag];
            out[t - 1] = (float)tag;
        }
    }
}

// ---------------------------------------------------------------------------
extern "C" void kernel_launch(void* const* d_in, const int* in_sizes, int n_in,
                              void* d_out, int out_size, void* d_ws, size_t ws_size,
                              hipStream_t stream)
{
    const int*   sentence = (const int*)  d_in[0];
    const float* emb      = (const float*)d_in[1];
    const float* wih_f    = (const float*)d_in[2];
    const float* whh_f    = (const float*)d_in[3];
    const float* bih_f    = (const float*)d_in[4];
    const float* bhh_f    = (const float*)d_in[5];
    const float* wih_b    = (const float*)d_in[6];
    const float* whh_b    = (const float*)d_in[7];
    const float* bih_b    = (const float*)d_in[8];
    const float* bhh_b    = (const float*)d_in[9];
    const float* wout     = (const float*)d_in[10];
    const float* bout     = (const float*)d_in[11];
    const float* trans    = (const float*)d_in[12];
    float* out = (float*)d_out;

    char* ws = (char*)d_ws;
    float* xg_f   = (float*)(ws + 1024);
    float* xg_b   = xg_f  + (size_t)L * G4;
    float* hfbuf  = xg_b  + (size_t)L * G4;
    float* hbbuf  = hfbuf + (size_t)L * HH;
    float* featsb = hbbuf + (size_t)L * HH;
    // total: 1024 + 2*L*G4*4 + 2*L*HH*4 + L*8*4  ~= 84 MB

    // h buffers -> sentinel (0xFF bytes = -NaN); data-arrival sync relies on it
    hipMemsetAsync(hfbuf, 0xFF, (size_t)2 * L * HH * sizeof(float), stream);

    hipLaunchKernelGGL(xg_kernel, dim3(L / 64, G4 / 64, 2), dim3(256), 0, stream,
                       sentence, emb, wih_f, bih_f, bhh_f, wih_b, bih_b, bhh_b,
                       xg_f, xg_b);

    void* args[] = { (void*)&xg_f, (void*)&xg_b, (void*)&whh_f, (void*)&whh_b,
                     (void*)&hfbuf, (void*)&hbbuf };
    hipLaunchCooperativeKernel((void*)lstm_kernel, dim3(2 * NBLK), dim3(512),
                               args, 0, stream);

    hipLaunchKernelGGL(feats_kernel, dim3(L), dim3(256), 0, stream,
                       hfbuf, hbbuf, wout, bout, featsb);

    hipLaunchKernelGGL(viterbi_kernel, dim3(1), dim3(64), 0, stream,
                       featsb, trans, out);
}